// Round 12
// baseline (81.099 us; speedup 1.0000x reference)
//
#include <hip/hip_runtime.h>
#include <hip/hip_bf16.h>
#include <hip/hip_fp8.h>

typedef __attribute__((ext_vector_type(4))) float f32x4;
typedef long long i64;

// exp(v/T - 5) with T=0.2  ==  exp2( (v-1) * 5*log2(e) )
#define EXP_SCALE 7.213475204444817f

__device__ __forceinline__ float fast_exp2(float x) {
#if __has_builtin(__builtin_amdgcn_exp2f)
  return __builtin_amdgcn_exp2f(x);
#else
  return exp2f(x);
#endif
}

// z is fp8 e4m3, SWIZZLED in MFMA-fragment order (byte units):
//   byte addr = tile*2048 + kk*512 + slot*8 + rem
// tile = row>>4, c = row&15; element e: kk = e>>5, q = (e>>3)&3, rem = e&7,
// slot = q*16 + c. A wave (lane = slot) loads one (tile,kk) fragment as one
// contiguous 512B wave load (8B/lane dwordx2) — R10's proven layout.

// Kernel 1: L2-normalize rows -> swizzled fp8 z. Block = one 16-row tile.
// Also zeroes rowsum (atomic target) and out[0].
__global__ __launch_bounds__(256) void k_normalize(
    const float* __restrict__ emb_i, const float* __restrict__ emb_j,
    unsigned char* __restrict__ z, float* __restrict__ rowsum,
    float* __restrict__ out)
{
  if (blockIdx.x == 0 && threadIdx.x == 0) out[0] = 0.0f;
  if (threadIdx.x < 16) rowsum[(blockIdx.x << 4) + threadIdx.x] = 0.0f;
  const int t = threadIdx.x;
  const int c = t >> 4;               // row within tile (0..15)
  const int sub = t & 15;             // 8-element block within row
  const int row = (blockIdx.x << 4) + c;
  const float* src = (row < 4096) ? (emb_i + row * 128) : (emb_j + (row - 4096) * 128);
  float4 v0 = reinterpret_cast<const float4*>(src)[sub * 2];
  float4 v1 = reinterpret_cast<const float4*>(src)[sub * 2 + 1];
  float ss = v0.x*v0.x + v0.y*v0.y + v0.z*v0.z + v0.w*v0.w
           + v1.x*v1.x + v1.y*v1.y + v1.z*v1.z + v1.w*v1.w;
  #pragma unroll
  for (int m = 1; m < 16; m <<= 1) ss += __shfl_xor(ss, m, 64);
  float rinv = 1.0f / sqrtf(ss);
  unsigned char st[8];
  st[0] = __hip_fp8_e4m3(v0.x * rinv).__x;
  st[1] = __hip_fp8_e4m3(v0.y * rinv).__x;
  st[2] = __hip_fp8_e4m3(v0.z * rinv).__x;
  st[3] = __hip_fp8_e4m3(v0.w * rinv).__x;
  st[4] = __hip_fp8_e4m3(v1.x * rinv).__x;
  st[5] = __hip_fp8_e4m3(v1.y * rinv).__x;
  st[6] = __hip_fp8_e4m3(v1.z * rinv).__x;
  st[7] = __hip_fp8_e4m3(v1.w * rinv).__x;
  // swizzled dst: kk = sub>>2, q = sub&3, slot = q*16 + c
  unsigned char* dst = z + blockIdx.x * 2048 + (sub >> 2) * 512 +
                       (((sub & 3) << 4) + c) * 8;
  *reinterpret_cast<i64*>(dst) = *reinterpret_cast<i64*>(st);
}

// Kernel 2 (symmetric, fp8 MFMA, distance-4 static pipeline): cell =
// 64 rows x 512 cols, launched iff rb < 8(ch+1), ch 0..15 -> 1088 cells.
// A straight from global (16 x 512B contiguous wave loads). B: 4 named
// buffers, 8-iter loop fully unrolled, prefetch distance 4 (all register
// indices static -> no scratch). Row-sums + transposed col-sums atomicAdd
// into rowsum. Diagonal exp term (==1) kept; k_finish subtracts 1.
__global__ __launch_bounds__(256, 3) void k_simlse(
    const unsigned char* __restrict__ z,
    float* __restrict__ rowsum,   // [8192], atomic accumulation
    float* __restrict__ rowpos)   // [4096] (row r>=4096 mirrors r-4096)
{
  const int w = threadIdx.x >> 6;
  const int lane = threadIdx.x & 63;
  const int q = lane >> 4;
  const int c = lane & 15;

  // cell id -> (ch, rb): start(ch) = 4ch(ch+1), cells(ch) = 8(ch+1)
  int ch = 0;
  while ((int)blockIdx.x >= 4 * (ch + 1) * (ch + 2)) ++ch;
  const int rb = blockIdx.x - 4 * ch * (ch + 1);   // 0 .. 8ch+7
  const int R0 = rb << 6;                          // 64-row block
  const bool upper = (rb < (ch << 3));             // strictly above diagonal band

  // ---- A fragments straight from global: 16 contiguous 512B loads ----
  i64 a[4][4];
  {
    const unsigned char* ap = z + (R0 >> 4) * 2048 + (lane << 3);
    #pragma unroll
    for (int rg = 0; rg < 4; ++rg)
      #pragma unroll
      for (int kk = 0; kk < 4; ++kk)
        a[rg][kk] = *reinterpret_cast<const i64*>(ap + rg * 2048 + kk * 512);
  }

  float acc[4][4];
  #pragma unroll
  for (int rg = 0; rg < 4; ++rg)
    #pragma unroll
    for (int e = 0; e < 4; ++e) acc[rg][e] = 0.0f;
  float pacc[4] = {0.f, 0.f, 0.f, 0.f};
  float colp[8];
  #pragma unroll
  for (int i = 0; i < 8; ++i) colp[i] = 0.0f;

  __shared__ float lsum[4][64];
  __shared__ float lpos[4][16];

  // wave w walks 16-col tiles ct = 32ch + w + 4i, i = 0..7
  const int ct0 = (ch << 5) + w;
  const unsigned char* bwave = z + ct0 * 2048 + (lane << 3);

  // positive tile: owned by this cell iff its 32-tile chunk matches.
  const int pos0t = ((R0 + 4096) & 8191) >> 4;
  const int ipb = ((pos0t >> 5) == ch) ? ((pos0t & 31) >> 2) : -99;

  i64 b0[4], b1[4], b2[4], b3[4];
  auto ldb = [&](i64 (&dst)[4], int idx) {
    const unsigned char* p = bwave + idx * 8192;   // stride 4 tiles = 8KB
    dst[0] = *reinterpret_cast<const i64*>(p);
    dst[1] = *reinterpret_cast<const i64*>(p + 512);
    dst[2] = *reinterpret_cast<const i64*>(p + 1024);
    dst[3] = *reinterpret_cast<const i64*>(p + 1536);
  };

  auto process = [&](const i64 (&bb)[4], int i) {
    f32x4 cc[4];
    #pragma unroll
    for (int rr = 0; rr < 4; ++rr) cc[rr] = f32x4{0.f, 0.f, 0.f, 0.f};
    #pragma unroll
    for (int kk = 0; kk < 4; ++kk)
      #pragma unroll
      for (int rr = 0; rr < 4; ++rr)
        cc[rr] = __builtin_amdgcn_mfma_f32_16x16x32_fp8_fp8(
            a[rr][kk], bb[kk], cc[rr], 0, 0, 0);
    float cp0 = 0.0f, cp1 = 0.0f;       // two chains to cut dep latency
    #pragma unroll
    for (int rr = 0; rr < 4; ++rr)
      #pragma unroll
      for (int e = 0; e < 4; ++e) {
        float tv = fast_exp2(__builtin_fmaf(cc[rr][e], EXP_SCALE, -EXP_SCALE));
        acc[rr][e] += tv;
        if (upper) { if (rr & 1) cp1 += tv; else cp0 += tv; }
      }
    if (upper) colp[i] = cp0 + cp1;     // shfl deferred out of the loop
    if (i == ipb) {                     // rare, wave-uniform
      #pragma unroll
      for (int rr = 0; rr < 4; ++rr) {
        if (rr == w) {
          #pragma unroll
          for (int e = 0; e < 4; ++e)
            if (c == ((q << 2) + e)) pacc[e] = cc[rr][e] * 5.0f;
        }
      }
    }
  };

  // Distance-4 software pipeline, fully static register indices
  ldb(b0, 0); ldb(b1, 1); ldb(b2, 2); ldb(b3, 3);
  process(b0, 0); ldb(b0, 4);
  process(b1, 1); ldb(b1, 5);
  process(b2, 2); ldb(b2, 6);
  process(b3, 3); ldb(b3, 7);
  process(b0, 4);
  process(b1, 5);
  process(b2, 6);
  process(b3, 7);

  // Deferred colsum reduction: 8 independent values, shfls pipeline
  if (upper) {
    #pragma unroll
    for (int i = 0; i < 8; ++i) {
      float v = colp[i];
      v += __shfl_xor(v, 16, 64);
      v += __shfl_xor(v, 32, 64);
      if (lane < 16)                    // col = (ct0+4i)*16 + c
        atomicAdd(&rowsum[((ct0 + (i << 2)) << 4) + c], v);
    }
  }

  // Reduce row-sums over the 16 cols per tile (c-group: xor 1,2,4,8)
  #pragma unroll
  for (int m = 1; m < 16; m <<= 1) {
    #pragma unroll
    for (int rg = 0; rg < 4; ++rg)
      #pragma unroll
      for (int e = 0; e < 4; ++e)
        acc[rg][e] += __shfl_xor(acc[rg][e], m, 64);
    #pragma unroll
    for (int e = 0; e < 4; ++e) pacc[e] += __shfl_xor(pacc[e], m, 64);
  }

  if (c == 0) {
    #pragma unroll
    for (int rg = 0; rg < 4; ++rg)
      #pragma unroll
      for (int e = 0; e < 4; ++e)
        lsum[w][rg * 16 + (q << 2) + e] = acc[rg][e];
    #pragma unroll
    for (int e = 0; e < 4; ++e) lpos[w][(q << 2) + e] = pacc[e];
  }
  __syncthreads();

  if (threadIdx.x < 64) {
    const int t = threadIdx.x;
    float s = lsum[0][t] + lsum[1][t] + lsum[2][t] + lsum[3][t];
    atomicAdd(&rowsum[R0 + t], s);
    if (ipb != -99)                     // this cell owns the positive cols
      rowpos[R0 + t] = lpos[t >> 4][t & 15];
  }
}

// Kernel 3: tot = rowsum - 1 (diagonal term); lse = 5 + log(tot);
// loss = mean(lse - pos). pos for r>=4096 mirrors r-4096 (S symmetric).
__global__ __launch_bounds__(256) void k_finish(
    const float* __restrict__ rowsum, const float* __restrict__ rowpos,
    float* __restrict__ out)
{
  const int r = blockIdx.x * 256 + threadIdx.x;
  float tot = rowsum[r] - 1.0f;
  float v = 5.0f + logf(tot) - rowpos[r & 4095];
  #pragma unroll
  for (int m = 1; m < 64; m <<= 1) v += __shfl_xor(v, m, 64);
  __shared__ float red[4];
  if ((threadIdx.x & 63) == 0) red[threadIdx.x >> 6] = v;
  __syncthreads();
  if (threadIdx.x == 0)
    atomicAdd(out, (red[0] + red[1] + red[2] + red[3]) * (1.0f / 8192.0f));
}

extern "C" void kernel_launch(void* const* d_in, const int* in_sizes, int n_in,
                              void* d_out, int out_size, void* d_ws, size_t ws_size,
                              hipStream_t stream) {
  const float* emb_i = (const float*)d_in[0];
  const float* emb_j = (const float*)d_in[1];
  unsigned char* z = (unsigned char*)d_ws;                         // 1 MB (fp8, swizzled)
  float* rowsum = (float*)((char*)d_ws + (1 << 20));               // [8192] = 32 KB
  float* rowpos = rowsum + 8192;                                   // [4096] = 16 KB
  float* out = (float*)d_out;

  k_normalize<<<512, 256, 0, stream>>>(emb_i, emb_j, z, rowsum, out);
  k_simlse<<<1088, 256, 0, stream>>>(z, rowsum, rowpos);
  k_finish<<<32, 256, 0, stream>>>(rowsum, rowpos, out);
}

// Round 13
// 76.321 us; speedup vs baseline: 1.0626x; 1.0626x over previous
//
#include <hip/hip_runtime.h>
#include <hip/hip_bf16.h>
#include <hip/hip_fp8.h>

typedef __attribute__((ext_vector_type(4))) float f32x4;
typedef long long i64;

// exp(v/T - 5) with T=0.2  ==  exp2( (v-1) * 5*log2(e) )
#define EXP_SCALE 7.213475204444817f

__device__ __forceinline__ float fast_exp2(float x) {
#if __has_builtin(__builtin_amdgcn_exp2f)
  return __builtin_amdgcn_exp2f(x);
#else
  return exp2f(x);
#endif
}

// z is stored as fp8 e4m3, SWIZZLED in MFMA-fragment order (byte units):
//   byte addr = tile*2048 + kk*512 + slot*8 + rem
// tile = row>>4, c = row&15; element e: kk = e>>5, q = (e>>3)&3, rem = e&7,
// slot = q*16 + c. A wave (lane = q*16+c) loads one (tile,kk) fragment as
// one contiguous 512B load (8B/lane dwordx2).

// Kernel 1: L2-normalize rows -> swizzled fp8 z. Block = one 16-row tile.
// Also zeroes rowsum (atomic target) and out[0].
__global__ __launch_bounds__(256) void k_normalize(
    const float* __restrict__ emb_i, const float* __restrict__ emb_j,
    unsigned char* __restrict__ z, float* __restrict__ rowsum,
    float* __restrict__ out)
{
  if (blockIdx.x == 0 && threadIdx.x == 0) out[0] = 0.0f;
  if (threadIdx.x < 16) rowsum[(blockIdx.x << 4) + threadIdx.x] = 0.0f;
  const int t = threadIdx.x;
  const int c = t >> 4;               // row within tile (0..15)
  const int sub = t & 15;             // 8-element block within row
  const int row = (blockIdx.x << 4) + c;
  const float* src = (row < 4096) ? (emb_i + row * 128) : (emb_j + (row - 4096) * 128);
  float4 v0 = reinterpret_cast<const float4*>(src)[sub * 2];
  float4 v1 = reinterpret_cast<const float4*>(src)[sub * 2 + 1];
  float ss = v0.x*v0.x + v0.y*v0.y + v0.z*v0.z + v0.w*v0.w
           + v1.x*v1.x + v1.y*v1.y + v1.z*v1.z + v1.w*v1.w;
  #pragma unroll
  for (int m = 1; m < 16; m <<= 1) ss += __shfl_xor(ss, m, 64);
  float rinv = 1.0f / sqrtf(ss);
  unsigned char st[8];
  st[0] = __hip_fp8_e4m3(v0.x * rinv).__x;
  st[1] = __hip_fp8_e4m3(v0.y * rinv).__x;
  st[2] = __hip_fp8_e4m3(v0.z * rinv).__x;
  st[3] = __hip_fp8_e4m3(v0.w * rinv).__x;
  st[4] = __hip_fp8_e4m3(v1.x * rinv).__x;
  st[5] = __hip_fp8_e4m3(v1.y * rinv).__x;
  st[6] = __hip_fp8_e4m3(v1.z * rinv).__x;
  st[7] = __hip_fp8_e4m3(v1.w * rinv).__x;
  // swizzled dst: kk = sub>>2, q = sub&3, slot = q*16 + c
  unsigned char* dst = z + blockIdx.x * 2048 + (sub >> 2) * 512 +
                       (((sub & 3) << 4) + c) * 8;
  *reinterpret_cast<i64*>(dst) = *reinterpret_cast<i64*>(st);
}

// Kernel 2 (symmetric, fp8 MFMA): cell = 64 rows x 512 cols, launched iff
// rb < 8(ch+1), ch 0..15 -> 1088 cells (53% of full work). A fragments
// straight from global (16 x 512B contiguous wave loads). Row-sums
// atomicAdd into rowsum; strictly-upper cells also atomicAdd column sums
// (transposed rows), cross-lane reduction deferred out of the loop.
// Diagonal exp term (==1 for unit rows) kept; k_finish subtracts 1.
__global__ __launch_bounds__(256, 4) void k_simlse(
    const unsigned char* __restrict__ z,
    float* __restrict__ rowsum,   // [8192], atomic accumulation
    float* __restrict__ rowpos)   // [4096] (row r>=4096 mirrors r-4096)
{
  const int w = threadIdx.x >> 6;
  const int lane = threadIdx.x & 63;
  const int q = lane >> 4;
  const int c = lane & 15;

  // cell id -> (ch, rb): start(ch) = 4ch(ch+1), cells(ch) = 8(ch+1)
  int ch = 0;
  while ((int)blockIdx.x >= 4 * (ch + 1) * (ch + 2)) ++ch;
  const int rb = blockIdx.x - 4 * ch * (ch + 1);   // 0 .. 8ch+7
  const int R0 = rb << 6;                          // 64-row block
  const bool upper = (rb < (ch << 3));             // strictly above diagonal band

  // ---- A fragments straight from global: 16 contiguous 512B loads ----
  i64 a[4][4];
  {
    const unsigned char* ap = z + (R0 >> 4) * 2048 + (lane << 3);
    #pragma unroll
    for (int rg = 0; rg < 4; ++rg)
      #pragma unroll
      for (int kk = 0; kk < 4; ++kk)
        a[rg][kk] = *reinterpret_cast<const i64*>(ap + rg * 2048 + kk * 512);
  }

  float acc[4][4];
  #pragma unroll
  for (int rg = 0; rg < 4; ++rg)
    #pragma unroll
    for (int e = 0; e < 4; ++e) acc[rg][e] = 0.0f;
  float pacc[4] = {0.f, 0.f, 0.f, 0.f};
  float colp[8];
  #pragma unroll
  for (int i = 0; i < 8; ++i) colp[i] = 0.0f;

  __shared__ float lsum[4][64];
  __shared__ float lpos[4][16];

  // wave w walks 16-col tiles ct = 32ch + w + 4i, i = 0..7
  const int ct0 = (ch << 5) + w;
  const unsigned char* bwave = z + ct0 * 2048 + (lane << 3);

  // positive tile: owned by this cell iff its 32-tile chunk matches.
  const int pos0t = ((R0 + 4096) & 8191) >> 4;
  const int ipb = ((pos0t >> 5) == ch) ? ((pos0t & 31) >> 2) : -99;

  i64 b0[4], b1[4];
  auto ldb = [&](i64 (&dst)[4], int idx) {
    const unsigned char* p = bwave + idx * 8192;   // stride 4 tiles = 8KB
    dst[0] = *reinterpret_cast<const i64*>(p);
    dst[1] = *reinterpret_cast<const i64*>(p + 512);
    dst[2] = *reinterpret_cast<const i64*>(p + 1024);
    dst[3] = *reinterpret_cast<const i64*>(p + 1536);
  };

  auto process = [&](const i64 (&bb)[4], int i) {
    f32x4 cc[4];
    #pragma unroll
    for (int rr = 0; rr < 4; ++rr) cc[rr] = f32x4{0.f, 0.f, 0.f, 0.f};
    #pragma unroll
    for (int kk = 0; kk < 4; ++kk)
      #pragma unroll
      for (int rr = 0; rr < 4; ++rr)
        cc[rr] = __builtin_amdgcn_mfma_f32_16x16x32_fp8_fp8(
            a[rr][kk], bb[kk], cc[rr], 0, 0, 0);
    float cp0 = 0.0f, cp1 = 0.0f;       // two chains to cut dep latency
    #pragma unroll
    for (int rr = 0; rr < 4; ++rr)
      #pragma unroll
      for (int e = 0; e < 4; ++e) {
        float tv = fast_exp2(__builtin_fmaf(cc[rr][e], EXP_SCALE, -EXP_SCALE));
        acc[rr][e] += tv;
        if (upper) { if (rr & 1) cp1 += tv; else cp0 += tv; }
      }
    if (upper) colp[i] = cp0 + cp1;     // shfl deferred out of the loop
    if (i == ipb) {                     // rare, wave-uniform
      #pragma unroll
      for (int rr = 0; rr < 4; ++rr) {
        if (rr == w) {
          #pragma unroll
          for (int e = 0; e < 4; ++e)
            if (c == ((q << 2) + e)) pacc[e] = cc[rr][e] * 5.0f;
        }
      }
    }
  };

  ldb(b0, 0);
  #pragma unroll 1
  for (int i = 0; i < 8; i += 2) {
    ldb(b1, i + 1);
    process(b0, i);
    if (i + 2 < 8) ldb(b0, i + 2);
    process(b1, i + 1);
  }

  // Deferred colsum reduction: 8 independent values, shfls pipeline
  if (upper) {
    #pragma unroll
    for (int i = 0; i < 8; ++i) {
      float v = colp[i];
      v += __shfl_xor(v, 16, 64);
      v += __shfl_xor(v, 32, 64);
      if (lane < 16)                    // col = (ct0+4i)*16 + c
        atomicAdd(&rowsum[((ct0 + (i << 2)) << 4) + c], v);
    }
  }

  // Reduce row-sums over the 16 cols per tile (c-group: xor 1,2,4,8)
  #pragma unroll
  for (int m = 1; m < 16; m <<= 1) {
    #pragma unroll
    for (int rg = 0; rg < 4; ++rg)
      #pragma unroll
      for (int e = 0; e < 4; ++e)
        acc[rg][e] += __shfl_xor(acc[rg][e], m, 64);
    #pragma unroll
    for (int e = 0; e < 4; ++e) pacc[e] += __shfl_xor(pacc[e], m, 64);
  }

  if (c == 0) {
    #pragma unroll
    for (int rg = 0; rg < 4; ++rg)
      #pragma unroll
      for (int e = 0; e < 4; ++e)
        lsum[w][rg * 16 + (q << 2) + e] = acc[rg][e];
    #pragma unroll
    for (int e = 0; e < 4; ++e) lpos[w][(q << 2) + e] = pacc[e];
  }
  __syncthreads();

  if (threadIdx.x < 64) {
    const int t = threadIdx.x;
    float s = lsum[0][t] + lsum[1][t] + lsum[2][t] + lsum[3][t];
    atomicAdd(&rowsum[R0 + t], s);
    if (ipb != -99)                     // this cell owns the positive cols
      rowpos[R0 + t] = lpos[t >> 4][t & 15];
  }
}

// Kernel 3: tot = rowsum - 1 (diagonal term); lse = 5 + log(tot);
// loss = mean(lse - pos). pos for r>=4096 mirrors r-4096 (S symmetric).
__global__ __launch_bounds__(256) void k_finish(
    const float* __restrict__ rowsum, const float* __restrict__ rowpos,
    float* __restrict__ out)
{
  const int r = blockIdx.x * 256 + threadIdx.x;
  float tot = rowsum[r] - 1.0f;
  float v = 5.0f + logf(tot) - rowpos[r & 4095];
  #pragma unroll
  for (int m = 1; m < 64; m <<= 1) v += __shfl_xor(v, m, 64);
  __shared__ float red[4];
  if ((threadIdx.x & 63) == 0) red[threadIdx.x >> 6] = v;
  __syncthreads();
  if (threadIdx.x == 0)
    atomicAdd(out, (red[0] + red[1] + red[2] + red[3]) * (1.0f / 8192.0f));
}

extern "C" void kernel_launch(void* const* d_in, const int* in_sizes, int n_in,
                              void* d_out, int out_size, void* d_ws, size_t ws_size,
                              hipStream_t stream) {
  const float* emb_i = (const float*)d_in[0];
  const float* emb_j = (const float*)d_in[1];
  unsigned char* z = (unsigned char*)d_ws;                         // 8192*128*1 = 1 MB (fp8, swizzled)
  float* rowsum = (float*)((char*)d_ws + (1 << 20));               // [8192] = 32 KB
  float* rowpos = rowsum + 8192;                                   // [4096] = 16 KB
  float* out = (float*)d_out;

  k_normalize<<<512, 256, 0, stream>>>(emb_i, emb_j, z, rowsum, out);
  k_simlse<<<1088, 256, 0, stream>>>(z, rowsum, rowpos);
  k_finish<<<32, 256, 0, stream>>>(rowsum, rowpos, out);
}